// Round 1
// baseline (155.929 us; speedup 1.0000x reference)
//
#include <hip/hip_runtime.h>
#include <math.h>

#define VN_EPS   1e-6f
#define NEG      0.2f
#define POS      0.8f   // 1 - NEG

typedef float v2f __attribute__((ext_vector_type(2)));
typedef float v4f __attribute__((ext_vector_type(4)));

// ---- DPP 16-lane (row) reductions: VALU-only, HW-verified R3-R8 ------------
template <int CTRL>
__device__ __forceinline__ float dpp_add(float v) {
    int s = __builtin_amdgcn_update_dpp(0, __float_as_int(v), CTRL, 0xf, 0xf, true);
    return v + __int_as_float(s);
}
__device__ __forceinline__ float row16_allsum(float v) {
    v = dpp_add<0x128>(v);  // row_ror:8
    v = dpp_add<0x124>(v);  // row_ror:4
    v = dpp_add<0x122>(v);  // row_ror:2
    v = dpp_add<0x121>(v);  // row_ror:1
    return v;
}
__device__ __forceinline__ float row16_sum15(float v) {
    v = dpp_add<0x118>(v);  // row_shr:8
    v = dpp_add<0x114>(v);  // row_shr:4
    v = dpp_add<0x112>(v);  // row_shr:2
    v = dpp_add<0x111>(v);  // row_shr:1
    return v;
}
// lane <-> lane^16 exchange (BitMode: xor=16, and=0x1F)
__device__ __forceinline__ float swz_xor16(float v) {
    return __int_as_float(__builtin_amdgcn_ds_swizzle(__float_as_int(v), 0x401F));
}

// R11: OCCUPANCY split. R5-R10 showed time pinned at ~41us with ~87% per-wave
// stall, insensitive to ILP (full unroll) and I$ (rolled) -> latency-bound at
// 4 waves/SIMD, and the GRID (4000 waves) was exactly the 4-wave residency of
// a 65-128 VGPR kernel. This version uses 32 lanes/point:
//   lane = p*32 + og*16 + k   (p: point-in-wave, og: half, k: neighbor)
// og splits the score-net o-loop (8 each + one ds_swizzle xor-16 reduce), the
// fold h-groups (4 each), and the post-phase outputs. Grid: 8000 waves.
// __launch_bounds__(128,8) caps VGPR at 64 so 8 waves/SIMD become resident.
// Small weight tables move to LDS (og makes their indices row-varying; LDS
// row-broadcast reads replace what used to be SGPR loads).
// NOTE (R6): scores sc[] are PER-NEIGHBOR — never dedup the fold across k.
// NOTE (R9): the fold must stay fp32 (normalize amplifies bf16 quantization).
__global__ __launch_bounds__(128, 8) void areconv_kernel(
    const float* __restrict__ q_pts,    // [N,3]
    const float* __restrict__ s_pts,    // [N2,3]
    const int*   __restrict__ nbr,      // [N,16]
    const float* __restrict__ wb,       // [3,256]
    const float* __restrict__ w_vn,     // [3,16]
    const float* __restrict__ wd_vn,    // [3,16]
    const float* __restrict__ w_h1,     // [16,8]
    const float* __restrict__ w_h2,     // [8,8]
    const float* __restrict__ b_h2,     // [8]
    const float* __restrict__ wd_relu,  // [32,32]
    const float* __restrict__ w_un,     // [32,64]
    const float* __restrict__ wd_un,    // [32,64]
    float* __restrict__ out,            // [N,64,3]
    int N)
{
    const float BN_SCALE = 0.999994993f;  // float32(1/sqrt(1+1e-5))

    // per-point staging, d-major [bp][d][h], stride 36 (144 B, v4f-aligned).
    // All traffic intra-wave -> in-order DS pipe + compiler lgkmcnt, no
    // barriers needed after the initial weight-stage barrier.
    __shared__ __align__(16) float featsA [4][3][36];
    __shared__ __align__(16) float feats2A[4][3][36];
    // weight tables (row-varying index under og-split -> LDS broadcast reads)
    __shared__ __align__(16) float swb  [768];  // [3][256]
    __shared__ __align__(16) float swvn [48];   // [3][16]
    __shared__ __align__(16) float swdvn[48];
    __shared__ __align__(16) float swh1 [128];  // [16][8]

    const int tid = threadIdx.x;
    if (tid < 48) { swvn[tid] = w_vn[tid]; swdvn[tid] = wd_vn[tid]; }
    swh1[tid] = w_h1[tid];
#pragma unroll
    for (int i = 0; i < 6; ++i) swb[tid + 128 * i] = wb[tid + 128 * i];
    __syncthreads();

    const int wv   = tid >> 6;        // 0..1
    const int lane = tid & 63;
    const int p    = lane >> 5;       // point-in-wave (0..1)
    const int og   = (lane >> 4) & 1; // half (DPP row = (p,og))
    const int k    = lane & 15;       // neighbor index
    const int bp   = wv * 2 + p;      // point slot in block (0..3)
    int n = blockIdx.x * 4 + bp;
    n = (n < N) ? n : (N - 1);        // N=16000 -> never clamps

    // ---- gather + center + cross -> local frame L[c][d] ------------------
    // (both og rows of a point redundantly gather the same neighbors; cheap)
    const float qx = q_pts[n * 3 + 0];
    const float qy = q_pts[n * 3 + 1];
    const float qz = q_pts[n * 3 + 2];
    const int   id = nbr[n * 16 + k];
    const float px = s_pts[id * 3 + 0] - qx;
    const float py = s_pts[id * 3 + 1] - qy;
    const float pz = s_pts[id * 3 + 2] - qz;

    const float cx = row16_allsum(px) * 0.0625f;
    const float cy = row16_allsum(py) * 0.0625f;
    const float cz = row16_allsum(pz) * 0.0625f;

    const float rx = py * cz - pz * cy;
    const float ry = pz * cx - px * cz;
    const float rz = px * cy - py * cx;

    const float L[3][3] = {{px, py, pz}, {cx, cy, cz}, {rx, ry, rz}};

    // ---- score net: og half does 8 of the 16 o's, then xor-16 reduce -----
    v2f t01 = {0.f, 0.f}, t23 = t01, t45 = t01, t67 = t01;
#pragma unroll 1
    for (int o8 = 0; o8 < 8; ++o8) {
        const int o = og * 8 + o8;
        const float wv0 = swvn[o],  wv1 = swvn[16 + o],  wv2 = swvn[32 + o];
        const float wd0 = swdvn[o], wd1 = swdvn[16 + o], wd2 = swdvn[32 + o];
        float pv[3], dv[3];
        float dot = 0.f, dsq = 0.f;
#pragma unroll
        for (int d = 0; d < 3; ++d) {
            const float pp = BN_SCALE * (L[0][d] * wv0 + L[1][d] * wv1 + L[2][d] * wv2);
            const float dd = L[0][d] * wd0 + L[1][d] * wd1 + L[2][d] * wd2;
            pv[d] = pp; dv[d] = dd;
            dot += pp * dd;
            dsq += dd * dd;
        }
        const float f = dot * __builtin_amdgcn_rcpf(dsq + VN_EPS);
        float acc = 0.f;
#pragma unroll
        for (int d = 0; d < 3; ++d) {
            const float corr = pv[d] - f * dv[d];
            const float sel  = (dot >= 0.f) ? pv[d] : corr;
            const float a    = NEG * pv[d] + POS * sel;
            acc += a * a;
        }
        const float s = __builtin_amdgcn_sqrtf(acc);
        t01 += s * (*(const v2f*)&swh1[o * 8 + 0]);
        t23 += s * (*(const v2f*)&swh1[o * 8 + 2]);
        t45 += s * (*(const v2f*)&swh1[o * 8 + 4]);
        t67 += s * (*(const v2f*)&swh1[o * 8 + 6]);
    }
    // cross-half reduce: partner row holds the other 8 o's partials
    t01[0] += swz_xor16(t01[0]);  t01[1] += swz_xor16(t01[1]);
    t23[0] += swz_xor16(t23[0]);  t23[1] += swz_xor16(t23[1]);
    t45[0] += swz_xor16(t45[0]);  t45[1] += swz_xor16(t45[1]);
    t67[0] += swz_xor16(t67[0]);  t67[1] += swz_xor16(t67[1]);

    float tt[8];
    tt[0] = fmaxf(t01[0] * BN_SCALE, 0.f);  tt[1] = fmaxf(t01[1] * BN_SCALE, 0.f);
    tt[2] = fmaxf(t23[0] * BN_SCALE, 0.f);  tt[3] = fmaxf(t23[1] * BN_SCALE, 0.f);
    tt[4] = fmaxf(t45[0] * BN_SCALE, 0.f);  tt[5] = fmaxf(t45[1] * BN_SCALE, 0.f);
    tt[6] = fmaxf(t67[0] * BN_SCALE, 0.f);  tt[7] = fmaxf(t67[1] * BN_SCALE, 0.f);

    // ---- 8->8 conv + bias, softmax (uniform across lanes; w_h2/b_h2 stay
    //      global -> SGPR loads). Redundant across og rows — fine. ---------
    float sc[8];
    float mx = -1e30f;
#pragma unroll
    for (int op = 0; op < 4; ++op) {
        v2f u = *(const v2f*)&b_h2[2 * op];
#pragma unroll
        for (int c = 0; c < 8; ++c)
            u += tt[c] * (*(const v2f*)&w_h2[c * 8 + 2 * op]);
        sc[2 * op + 0] = u[0];
        sc[2 * op + 1] = u[1];
        mx = fmaxf(mx, fmaxf(u[0], u[1]));
    }
    float se = 0.f;
#pragma unroll
    for (int o = 0; o < 8; ++o) { sc[o] = __expf(sc[o] - mx); se += sc[o]; }
    const float inv_se = __builtin_amdgcn_rcpf(se);
#pragma unroll
    for (int o = 0; o < 8; ++o) sc[o] *= inv_se;

    // ---- kernel-point correlation: og half folds its 4 h-groups ----------
#pragma unroll 1
    for (int gi = 0; gi < 4; ++gi) {
        const int hb = og * 16 + gi * 4;
        v4f W0 = sc[0] * (*(const v4f*)&swb[0 * 256 + hb]);
        v4f W1 = sc[0] * (*(const v4f*)&swb[1 * 256 + hb]);
        v4f W2 = sc[0] * (*(const v4f*)&swb[2 * 256 + hb]);
#pragma unroll
        for (int s = 1; s < 8; ++s) {
            const float sv = sc[s];
            W0 += sv * (*(const v4f*)&swb[0 * 256 + s * 32 + hb]);
            W1 += sv * (*(const v4f*)&swb[1 * 256 + s * 32 + hb]);
            W2 += sv * (*(const v4f*)&swb[2 * 256 + s * 32 + hb]);
        }
        v4f V0 = L[0][0] * W0 + L[1][0] * W1 + L[2][0] * W2;
        v4f V1 = L[0][1] * W0 + L[1][1] * W1 + L[2][1] * W2;
        v4f V2 = L[0][2] * W0 + L[1][2] * W1 + L[2][2] * W2;
        const v4f vv = V0 * V0 + V1 * V1 + V2 * V2;
#pragma unroll
        for (int e = 0; e < 4; ++e) {
            const float inn = __builtin_amdgcn_rsqf(fmaxf(vv[e], 1e-24f)) * 0.0625f;
            V0[e] = row16_sum15(V0[e] * inn);
            V1[e] = row16_sum15(V1[e] * inn);
            V2[e] = row16_sum15(V2[e] * inn);
        }
        if (k == 15) {
            *(v4f*)&featsA[bp][0][hb] = V0;
            *(v4f*)&featsA[bp][1][hb] = V1;
            *(v4f*)&featsA[bp][2][hb] = V2;
        }
    }
    // intra-wave LDS write->read (in-order DS pipe + compiler lgkmcnt)

    const int oo = og * 16 + k;   // this lane's output channel (0..31)

    // ---- VNLeakyReLU(32->32): lane owns ONE o = oo ----------------------
    {
        float D0 = 0.f, D1 = 0.f, D2 = 0.f;
#pragma unroll 1
        for (int grp = 0; grp < 8; ++grp) {
            const int hb = grp * 4;
            const v4f f0 = *(const v4f*)&featsA[bp][0][hb];
            const v4f f1 = *(const v4f*)&featsA[bp][1][hb];
            const v4f f2 = *(const v4f*)&featsA[bp][2][hb];
#pragma unroll
            for (int e = 0; e < 4; ++e) {
                const float w = wd_relu[(hb + e) * 32 + oo];
                D0 += f0[e] * w;
                D1 += f1[e] * w;
                D2 += f2[e] * w;
            }
        }
        const float p0 = featsA[bp][0][oo];
        const float p1 = featsA[bp][1][oo];
        const float p2 = featsA[bp][2][oo];
        const float dot = p0 * D0 + p1 * D1 + p2 * D2;
        const float dsq = D0 * D0 + D1 * D1 + D2 * D2;
        const float f   = dot * __builtin_amdgcn_rcpf(dsq + VN_EPS);
        const bool  pos = (dot >= 0.f);
        feats2A[bp][0][oo] = NEG * p0 + POS * (pos ? p0 : (p0 - f * D0));
        feats2A[bp][1][oo] = NEG * p1 + POS * (pos ? p1 : (p1 - f * D1));
        feats2A[bp][2][oo] = NEG * p2 + POS * (pos ? p2 : (p2 - f * D2));
    }

    // ---- VNLinearLeakyReLU(32->64): lane owns o = {2oo, 2oo+1} ----------
    {
        v2f AU0 = {0.f, 0.f}, AU1 = AU0, AU2 = AU0;
        v2f AV0 = AU0, AV1 = AU0, AV2 = AU0;
#pragma unroll 1
        for (int grp = 0; grp < 8; ++grp) {
            const int hb = grp * 4;
            const v4f f0 = *(const v4f*)&feats2A[bp][0][hb];
            const v4f f1 = *(const v4f*)&feats2A[bp][1][hb];
            const v4f f2 = *(const v4f*)&feats2A[bp][2][hb];
#pragma unroll
            for (int e = 0; e < 4; ++e) {
                const v2f wu = *(const v2f*)&w_un [(hb + e) * 64 + 2 * oo];
                const v2f wd = *(const v2f*)&wd_un[(hb + e) * 64 + 2 * oo];
                AU0 += f0[e] * wu; AU1 += f1[e] * wu; AU2 += f2[e] * wu;
                AV0 += f0[e] * wd; AV1 += f1[e] * wd; AV2 += f2[e] * wd;
            }
        }
        float O[6];
#pragma unroll
        for (int j = 0; j < 2; ++j) {
            const float u0 = AU0[j] * BN_SCALE;
            const float u1 = AU1[j] * BN_SCALE;
            const float u2 = AU2[j] * BN_SCALE;
            const float v0 = AV0[j], v1 = AV1[j], v2 = AV2[j];
            const float dot = u0 * v0 + u1 * v1 + u2 * v2;
            const float dsq = v0 * v0 + v1 * v1 + v2 * v2;
            const float f   = dot * __builtin_amdgcn_rcpf(dsq + VN_EPS);
            const bool  pos = (dot >= 0.f);
            O[3 * j + 0] = NEG * u0 + POS * (pos ? u0 : (u0 - f * v0));
            O[3 * j + 1] = NEG * u1 + POS * (pos ? u1 : (u1 - f * v1));
            O[3 * j + 2] = NEG * u2 + POS * (pos ? u2 : (u2 - f * v2));
        }
        // lane oo covers out[n, 2oo..2oo+2, :] = 6 contiguous floats; 32
        // lanes cover the point's whole 192-float slab contiguously.
        // (oo*24 B is only 8-aligned -> three v2f stores, not v4f)
        float* dst = out + (long)n * 192 + 6 * oo;
        *(v2f*)(dst + 0) = *(const v2f*)&O[0];
        *(v2f*)(dst + 2) = *(const v2f*)&O[2];
        *(v2f*)(dst + 4) = *(const v2f*)&O[4];
    }
}

extern "C" void kernel_launch(void* const* d_in, const int* in_sizes, int n_in,
                              void* d_out, int out_size, void* d_ws, size_t ws_size,
                              hipStream_t stream) {
    const float* q_pts   = (const float*)d_in[0];
    const float* s_pts   = (const float*)d_in[1];
    // d_in[2] = s_feats: unused by the reference
    const int*   nbr     = (const int*)  d_in[3];
    const float* wb      = (const float*)d_in[4];
    const float* w_vn    = (const float*)d_in[5];
    const float* wd_vn   = (const float*)d_in[6];
    const float* w_h1    = (const float*)d_in[7];
    const float* w_h2    = (const float*)d_in[8];
    const float* b_h2    = (const float*)d_in[9];
    const float* wd_relu = (const float*)d_in[10];
    const float* w_un    = (const float*)d_in[11];
    const float* wd_un   = (const float*)d_in[12];
    float* out = (float*)d_out;

    const int N = in_sizes[0] / 3;          // q_pts is [N,3]
    const int blocks = (N + 3) / 4;         // 4 points/block, 2 per wave
    areconv_kernel<<<blocks, 128, 0, stream>>>(
        q_pts, s_pts, nbr, wb, w_vn, wd_vn, w_h1, w_h2, b_h2,
        wd_relu, w_un, wd_un, out, N);
}

// Round 2
// 129.212 us; speedup vs baseline: 1.2068x; 1.2068x over previous
//
#include <hip/hip_runtime.h>
#include <math.h>

#define VN_EPS   1e-6f
#define NEG      0.2f
#define POS      0.8f   // 1 - NEG

typedef float v2f __attribute__((ext_vector_type(2)));
typedef float v4f __attribute__((ext_vector_type(4)));

// ---- DPP 16-lane (row) reductions: VALU-only, HW-verified R3-R8 ------------
template <int CTRL>
__device__ __forceinline__ float dpp_add(float v) {
    int s = __builtin_amdgcn_update_dpp(0, __float_as_int(v), CTRL, 0xf, 0xf, true);
    return v + __int_as_float(s);
}
__device__ __forceinline__ float row16_allsum(float v) {
    v = dpp_add<0x128>(v);  // row_ror:8
    v = dpp_add<0x124>(v);  // row_ror:4
    v = dpp_add<0x122>(v);  // row_ror:2
    v = dpp_add<0x121>(v);  // row_ror:1
    return v;
}
__device__ __forceinline__ float row16_sum15(float v) {
    v = dpp_add<0x118>(v);  // row_shr:8
    v = dpp_add<0x114>(v);  // row_shr:4
    v = dpp_add<0x112>(v);  // row_shr:2
    v = dpp_add<0x111>(v);  // row_shr:1
    return v;
}
// lane <-> lane^16 exchange (BitMode: xor=16, and=0x1F)
__device__ __forceinline__ float swz_xor16(float v) {
    return __int_as_float(__builtin_amdgcn_ds_swizzle(__float_as_int(v), 0x401F));
}

// R12: same 32-lane/point split as R11 (grid = 8000 waves), but the (128,8)
// launch bound forced VGPR=32 and the compiler SPILLED (~200MB scratch
// traffic: FETCH 138MB, WRITE 88MB vs ~14MB ideal). Natural register demand
// is ~90-100. Relax to (128,6): cap = floor(512/6) = 85 VGPR -> 6 waves/SIMD
// resident (1.5x the R10 baseline's 4) with little/no spill.
//   lane = p*32 + og*16 + k   (p: point-in-wave, og: half, k: neighbor)
// NOTE (R6): scores sc[] are PER-NEIGHBOR — never dedup the fold across k.
// NOTE (R9): the fold must stay fp32 (normalize amplifies bf16 quantization).
// NOTE (R11): never force the 64-VGPR class on this kernel — it spills ~10x
// the kernel's ideal HBM traffic.
__global__ __launch_bounds__(128, 6) void areconv_kernel(
    const float* __restrict__ q_pts,    // [N,3]
    const float* __restrict__ s_pts,    // [N2,3]
    const int*   __restrict__ nbr,      // [N,16]
    const float* __restrict__ wb,       // [3,256]
    const float* __restrict__ w_vn,     // [3,16]
    const float* __restrict__ wd_vn,    // [3,16]
    const float* __restrict__ w_h1,     // [16,8]
    const float* __restrict__ w_h2,     // [8,8]
    const float* __restrict__ b_h2,     // [8]
    const float* __restrict__ wd_relu,  // [32,32]
    const float* __restrict__ w_un,     // [32,64]
    const float* __restrict__ wd_un,    // [32,64]
    float* __restrict__ out,            // [N,64,3]
    int N)
{
    const float BN_SCALE = 0.999994993f;  // float32(1/sqrt(1+1e-5))

    // per-point staging, d-major [bp][d][h], stride 36 (144 B, v4f-aligned).
    // All traffic intra-wave -> in-order DS pipe + compiler lgkmcnt, no
    // barriers needed after the initial weight-stage barrier.
    __shared__ __align__(16) float featsA [4][3][36];
    __shared__ __align__(16) float feats2A[4][3][36];
    // weight tables (row-varying index under og-split -> LDS broadcast reads)
    __shared__ __align__(16) float swb  [768];  // [3][256]
    __shared__ __align__(16) float swvn [48];   // [3][16]
    __shared__ __align__(16) float swdvn[48];
    __shared__ __align__(16) float swh1 [128];  // [16][8]

    const int tid = threadIdx.x;
    if (tid < 48) { swvn[tid] = w_vn[tid]; swdvn[tid] = wd_vn[tid]; }
    swh1[tid] = w_h1[tid];
#pragma unroll
    for (int i = 0; i < 6; ++i) swb[tid + 128 * i] = wb[tid + 128 * i];
    __syncthreads();

    const int wv   = tid >> 6;        // 0..1
    const int lane = tid & 63;
    const int p    = lane >> 5;       // point-in-wave (0..1)
    const int og   = (lane >> 4) & 1; // half (DPP row = (p,og))
    const int k    = lane & 15;       // neighbor index
    const int bp   = wv * 2 + p;      // point slot in block (0..3)
    int n = blockIdx.x * 4 + bp;
    n = (n < N) ? n : (N - 1);        // N=16000 -> never clamps

    // ---- gather + center + cross -> local frame L[c][d] ------------------
    // (both og rows of a point redundantly gather the same neighbors; cheap)
    const float qx = q_pts[n * 3 + 0];
    const float qy = q_pts[n * 3 + 1];
    const float qz = q_pts[n * 3 + 2];
    const int   id = nbr[n * 16 + k];
    const float px = s_pts[id * 3 + 0] - qx;
    const float py = s_pts[id * 3 + 1] - qy;
    const float pz = s_pts[id * 3 + 2] - qz;

    const float cx = row16_allsum(px) * 0.0625f;
    const float cy = row16_allsum(py) * 0.0625f;
    const float cz = row16_allsum(pz) * 0.0625f;

    const float rx = py * cz - pz * cy;
    const float ry = pz * cx - px * cz;
    const float rz = px * cy - py * cx;

    const float L[3][3] = {{px, py, pz}, {cx, cy, cz}, {rx, ry, rz}};

    // ---- score net: og half does 8 of the 16 o's, then xor-16 reduce -----
    v2f t01 = {0.f, 0.f}, t23 = t01, t45 = t01, t67 = t01;
#pragma unroll 1
    for (int o8 = 0; o8 < 8; ++o8) {
        const int o = og * 8 + o8;
        const float wv0 = swvn[o],  wv1 = swvn[16 + o],  wv2 = swvn[32 + o];
        const float wd0 = swdvn[o], wd1 = swdvn[16 + o], wd2 = swdvn[32 + o];
        float pv[3], dv[3];
        float dot = 0.f, dsq = 0.f;
#pragma unroll
        for (int d = 0; d < 3; ++d) {
            const float pp = BN_SCALE * (L[0][d] * wv0 + L[1][d] * wv1 + L[2][d] * wv2);
            const float dd = L[0][d] * wd0 + L[1][d] * wd1 + L[2][d] * wd2;
            pv[d] = pp; dv[d] = dd;
            dot += pp * dd;
            dsq += dd * dd;
        }
        const float f = dot * __builtin_amdgcn_rcpf(dsq + VN_EPS);
        float acc = 0.f;
#pragma unroll
        for (int d = 0; d < 3; ++d) {
            const float corr = pv[d] - f * dv[d];
            const float sel  = (dot >= 0.f) ? pv[d] : corr;
            const float a    = NEG * pv[d] + POS * sel;
            acc += a * a;
        }
        const float s = __builtin_amdgcn_sqrtf(acc);
        t01 += s * (*(const v2f*)&swh1[o * 8 + 0]);
        t23 += s * (*(const v2f*)&swh1[o * 8 + 2]);
        t45 += s * (*(const v2f*)&swh1[o * 8 + 4]);
        t67 += s * (*(const v2f*)&swh1[o * 8 + 6]);
    }
    // cross-half reduce: partner row holds the other 8 o's partials
    t01[0] += swz_xor16(t01[0]);  t01[1] += swz_xor16(t01[1]);
    t23[0] += swz_xor16(t23[0]);  t23[1] += swz_xor16(t23[1]);
    t45[0] += swz_xor16(t45[0]);  t45[1] += swz_xor16(t45[1]);
    t67[0] += swz_xor16(t67[0]);  t67[1] += swz_xor16(t67[1]);

    float tt[8];
    tt[0] = fmaxf(t01[0] * BN_SCALE, 0.f);  tt[1] = fmaxf(t01[1] * BN_SCALE, 0.f);
    tt[2] = fmaxf(t23[0] * BN_SCALE, 0.f);  tt[3] = fmaxf(t23[1] * BN_SCALE, 0.f);
    tt[4] = fmaxf(t45[0] * BN_SCALE, 0.f);  tt[5] = fmaxf(t45[1] * BN_SCALE, 0.f);
    tt[6] = fmaxf(t67[0] * BN_SCALE, 0.f);  tt[7] = fmaxf(t67[1] * BN_SCALE, 0.f);

    // ---- 8->8 conv + bias, softmax (uniform across lanes; w_h2/b_h2 stay
    //      global -> SGPR loads). Redundant across og rows — fine. ---------
    float sc[8];
    float mx = -1e30f;
#pragma unroll
    for (int op = 0; op < 4; ++op) {
        v2f u = *(const v2f*)&b_h2[2 * op];
#pragma unroll
        for (int c = 0; c < 8; ++c)
            u += tt[c] * (*(const v2f*)&w_h2[c * 8 + 2 * op]);
        sc[2 * op + 0] = u[0];
        sc[2 * op + 1] = u[1];
        mx = fmaxf(mx, fmaxf(u[0], u[1]));
    }
    float se = 0.f;
#pragma unroll
    for (int o = 0; o < 8; ++o) { sc[o] = __expf(sc[o] - mx); se += sc[o]; }
    const float inv_se = __builtin_amdgcn_rcpf(se);
#pragma unroll
    for (int o = 0; o < 8; ++o) sc[o] *= inv_se;

    // ---- kernel-point correlation: og half folds its 4 h-groups ----------
#pragma unroll 1
    for (int gi = 0; gi < 4; ++gi) {
        const int hb = og * 16 + gi * 4;
        v4f W0 = sc[0] * (*(const v4f*)&swb[0 * 256 + hb]);
        v4f W1 = sc[0] * (*(const v4f*)&swb[1 * 256 + hb]);
        v4f W2 = sc[0] * (*(const v4f*)&swb[2 * 256 + hb]);
#pragma unroll
        for (int s = 1; s < 8; ++s) {
            const float sv = sc[s];
            W0 += sv * (*(const v4f*)&swb[0 * 256 + s * 32 + hb]);
            W1 += sv * (*(const v4f*)&swb[1 * 256 + s * 32 + hb]);
            W2 += sv * (*(const v4f*)&swb[2 * 256 + s * 32 + hb]);
        }
        v4f V0 = L[0][0] * W0 + L[1][0] * W1 + L[2][0] * W2;
        v4f V1 = L[0][1] * W0 + L[1][1] * W1 + L[2][1] * W2;
        v4f V2 = L[0][2] * W0 + L[1][2] * W1 + L[2][2] * W2;
        const v4f vv = V0 * V0 + V1 * V1 + V2 * V2;
#pragma unroll
        for (int e = 0; e < 4; ++e) {
            const float inn = __builtin_amdgcn_rsqf(fmaxf(vv[e], 1e-24f)) * 0.0625f;
            V0[e] = row16_sum15(V0[e] * inn);
            V1[e] = row16_sum15(V1[e] * inn);
            V2[e] = row16_sum15(V2[e] * inn);
        }
        if (k == 15) {
            *(v4f*)&featsA[bp][0][hb] = V0;
            *(v4f*)&featsA[bp][1][hb] = V1;
            *(v4f*)&featsA[bp][2][hb] = V2;
        }
    }
    // intra-wave LDS write->read (in-order DS pipe + compiler lgkmcnt)

    const int oo = og * 16 + k;   // this lane's output channel (0..31)

    // ---- VNLeakyReLU(32->32): lane owns ONE o = oo ----------------------
    {
        float D0 = 0.f, D1 = 0.f, D2 = 0.f;
#pragma unroll 1
        for (int grp = 0; grp < 8; ++grp) {
            const int hb = grp * 4;
            const v4f f0 = *(const v4f*)&featsA[bp][0][hb];
            const v4f f1 = *(const v4f*)&featsA[bp][1][hb];
            const v4f f2 = *(const v4f*)&featsA[bp][2][hb];
#pragma unroll
            for (int e = 0; e < 4; ++e) {
                const float w = wd_relu[(hb + e) * 32 + oo];
                D0 += f0[e] * w;
                D1 += f1[e] * w;
                D2 += f2[e] * w;
            }
        }
        const float p0 = featsA[bp][0][oo];
        const float p1 = featsA[bp][1][oo];
        const float p2 = featsA[bp][2][oo];
        const float dot = p0 * D0 + p1 * D1 + p2 * D2;
        const float dsq = D0 * D0 + D1 * D1 + D2 * D2;
        const float f   = dot * __builtin_amdgcn_rcpf(dsq + VN_EPS);
        const bool  pos = (dot >= 0.f);
        feats2A[bp][0][oo] = NEG * p0 + POS * (pos ? p0 : (p0 - f * D0));
        feats2A[bp][1][oo] = NEG * p1 + POS * (pos ? p1 : (p1 - f * D1));
        feats2A[bp][2][oo] = NEG * p2 + POS * (pos ? p2 : (p2 - f * D2));
    }

    // ---- VNLinearLeakyReLU(32->64): lane owns o = {2oo, 2oo+1} ----------
    {
        v2f AU0 = {0.f, 0.f}, AU1 = AU0, AU2 = AU0;
        v2f AV0 = AU0, AV1 = AU0, AV2 = AU0;
#pragma unroll 1
        for (int grp = 0; grp < 8; ++grp) {
            const int hb = grp * 4;
            const v4f f0 = *(const v4f*)&feats2A[bp][0][hb];
            const v4f f1 = *(const v4f*)&feats2A[bp][1][hb];
            const v4f f2 = *(const v4f*)&feats2A[bp][2][hb];
#pragma unroll
            for (int e = 0; e < 4; ++e) {
                const v2f wu = *(const v2f*)&w_un [(hb + e) * 64 + 2 * oo];
                const v2f wd = *(const v2f*)&wd_un[(hb + e) * 64 + 2 * oo];
                AU0 += f0[e] * wu; AU1 += f1[e] * wu; AU2 += f2[e] * wu;
                AV0 += f0[e] * wd; AV1 += f1[e] * wd; AV2 += f2[e] * wd;
            }
        }
        float O[6];
#pragma unroll
        for (int j = 0; j < 2; ++j) {
            const float u0 = AU0[j] * BN_SCALE;
            const float u1 = AU1[j] * BN_SCALE;
            const float u2 = AU2[j] * BN_SCALE;
            const float v0 = AV0[j], v1 = AV1[j], v2 = AV2[j];
            const float dot = u0 * v0 + u1 * v1 + u2 * v2;
            const float dsq = v0 * v0 + v1 * v1 + v2 * v2;
            const float f   = dot * __builtin_amdgcn_rcpf(dsq + VN_EPS);
            const bool  pos = (dot >= 0.f);
            O[3 * j + 0] = NEG * u0 + POS * (pos ? u0 : (u0 - f * v0));
            O[3 * j + 1] = NEG * u1 + POS * (pos ? u1 : (u1 - f * v1));
            O[3 * j + 2] = NEG * u2 + POS * (pos ? u2 : (u2 - f * v2));
        }
        // lane oo covers out[n, 2oo..2oo+2, :] = 6 contiguous floats; 32
        // lanes cover the point's whole 192-float slab contiguously.
        // (oo*24 B is only 8-aligned -> three v2f stores, not v4f)
        float* dst = out + (long)n * 192 + 6 * oo;
        *(v2f*)(dst + 0) = *(const v2f*)&O[0];
        *(v2f*)(dst + 2) = *(const v2f*)&O[2];
        *(v2f*)(dst + 4) = *(const v2f*)&O[4];
    }
}

extern "C" void kernel_launch(void* const* d_in, const int* in_sizes, int n_in,
                              void* d_out, int out_size, void* d_ws, size_t ws_size,
                              hipStream_t stream) {
    const float* q_pts   = (const float*)d_in[0];
    const float* s_pts   = (const float*)d_in[1];
    // d_in[2] = s_feats: unused by the reference
    const int*   nbr     = (const int*)  d_in[3];
    const float* wb      = (const float*)d_in[4];
    const float* w_vn    = (const float*)d_in[5];
    const float* w_h1    = (const float*)d_in[7];
    const float* wd_vn   = (const float*)d_in[6];
    const float* w_h2    = (const float*)d_in[8];
    const float* b_h2    = (const float*)d_in[9];
    const float* wd_relu = (const float*)d_in[10];
    const float* w_un    = (const float*)d_in[11];
    const float* wd_un   = (const float*)d_in[12];
    float* out = (float*)d_out;

    const int N = in_sizes[0] / 3;          // q_pts is [N,3]
    const int blocks = (N + 3) / 4;         // 4 points/block, 2 per wave
    areconv_kernel<<<blocks, 128, 0, stream>>>(
        q_pts, s_pts, nbr, wb, w_vn, wd_vn, w_h1, w_h2, b_h2,
        wd_relu, w_un, wd_un, out, N);
}

// Round 3
// 124.927 us; speedup vs baseline: 1.2482x; 1.0343x over previous
//
#include <hip/hip_runtime.h>
#include <math.h>

#define VN_EPS   1e-6f
#define NEG      0.2f
#define POS      0.8f   // 1 - NEG

typedef float v2f __attribute__((ext_vector_type(2)));
typedef float v4f __attribute__((ext_vector_type(4)));

// ---- DPP 16-lane (row) reductions: VALU-only, HW-verified R3-R8 ------------
template <int CTRL>
__device__ __forceinline__ float dpp_add(float v) {
    int s = __builtin_amdgcn_update_dpp(0, __float_as_int(v), CTRL, 0xf, 0xf, true);
    return v + __int_as_float(s);
}
__device__ __forceinline__ float row16_allsum(float v) {
    v = dpp_add<0x128>(v);  // row_ror:8
    v = dpp_add<0x124>(v);  // row_ror:4
    v = dpp_add<0x122>(v);  // row_ror:2
    v = dpp_add<0x121>(v);  // row_ror:1
    return v;
}
__device__ __forceinline__ float row16_sum15(float v) {
    v = dpp_add<0x118>(v);  // row_shr:8
    v = dpp_add<0x114>(v);  // row_shr:4
    v = dpp_add<0x112>(v);  // row_shr:2
    v = dpp_add<0x111>(v);  // row_shr:1
    return v;
}
// lane <-> lane^16 exchange (BitMode: xor=16, and=0x1F)
__device__ __forceinline__ float swz_xor16(float v) {
    return __int_as_float(__builtin_amdgcn_ds_swizzle(__float_as_int(v), 0x401F));
}

// R13: TWO-KERNEL SPLIT. R11/R12 established: the og-split grid (8000 waves)
// raises occupancy but the monolithic kernel's natural VGPR demand (>80)
// forces spilling at any cap that buys waves (R12: 80 VGPR cap -> 54MB
// scratch). Split so each phase pays only its own register pressure:
//   k1 (score+softmax+fold, ~75% of work): v2f fold chunks -> natural ~60,
//      (128,7) cap 72, no spill, 7 waves/SIMD (vs 4 in the R10 baseline).
//   k2 (two small VN layers): ~35 VGPR under (256,8), ~8 waves/SIMD.
// Handoff: k1 writes feats (96 floats/point) into the FIRST 96 floats of the
// point's 192-float out slab; k2 stages them to LDS then overwrites the slab.
// Per-thread load->LDS->compute->store dependency chain orders the slab read
// before the slab write; kernel boundary (stream order) orders k1 vs k2.
// NOTE (R6): scores sc[] are PER-NEIGHBOR — never dedup the fold across k.
// NOTE (R9): the fold must stay fp32 (normalize amplifies bf16 quantization).
// NOTE (R11/R12): never cap this work below its natural VGPR demand.
__global__ __launch_bounds__(128, 7) void areconv_fold(
    const float* __restrict__ q_pts,    // [N,3]
    const float* __restrict__ s_pts,    // [N2,3]
    const int*   __restrict__ nbr,      // [N,16]
    const float* __restrict__ wb,       // [3,256]
    const float* __restrict__ w_vn,     // [3,16]
    const float* __restrict__ wd_vn,    // [3,16]
    const float* __restrict__ w_h1,     // [16,8]
    const float* __restrict__ w_h2,     // [8,8]
    const float* __restrict__ b_h2,     // [8]
    float* __restrict__ out,            // [N,64,3]; feats staged in first 96
    int N)
{
    const float BN_SCALE = 0.999994993f;  // float32(1/sqrt(1+1e-5))

    // weight tables (row-varying index under og-split -> LDS broadcast reads)
    __shared__ __align__(16) float swb  [768];  // [3][256]
    __shared__ __align__(16) float swvn [48];   // [3][16]
    __shared__ __align__(16) float swdvn[48];
    __shared__ __align__(16) float swh1 [128];  // [16][8]

    const int tid = threadIdx.x;
    if (tid < 48) { swvn[tid] = w_vn[tid]; swdvn[tid] = wd_vn[tid]; }
    swh1[tid] = w_h1[tid];
#pragma unroll
    for (int i = 0; i < 6; ++i) swb[tid + 128 * i] = wb[tid + 128 * i];
    __syncthreads();

    const int wv   = tid >> 6;        // 0..1
    const int lane = tid & 63;
    const int p    = lane >> 5;       // point-in-wave (0..1)
    const int og   = (lane >> 4) & 1; // half (DPP row = (p,og))
    const int k    = lane & 15;       // neighbor index
    const int bp   = wv * 2 + p;      // point slot in block (0..3)
    int n = blockIdx.x * 4 + bp;
    n = (n < N) ? n : (N - 1);        // N=16000 -> never clamps

    // ---- gather + center + cross -> local frame L[c][d] ------------------
    const float qx = q_pts[n * 3 + 0];
    const float qy = q_pts[n * 3 + 1];
    const float qz = q_pts[n * 3 + 2];
    const int   id = nbr[n * 16 + k];
    const float px = s_pts[id * 3 + 0] - qx;
    const float py = s_pts[id * 3 + 1] - qy;
    const float pz = s_pts[id * 3 + 2] - qz;

    const float cx = row16_allsum(px) * 0.0625f;
    const float cy = row16_allsum(py) * 0.0625f;
    const float cz = row16_allsum(pz) * 0.0625f;

    const float rx = py * cz - pz * cy;
    const float ry = pz * cx - px * cz;
    const float rz = px * cy - py * cx;

    const float L[3][3] = {{px, py, pz}, {cx, cy, cz}, {rx, ry, rz}};

    // ---- score net: og half does 8 of the 16 o's, then xor-16 reduce -----
    v2f t01 = {0.f, 0.f}, t23 = t01, t45 = t01, t67 = t01;
#pragma unroll 1
    for (int o8 = 0; o8 < 8; ++o8) {
        const int o = og * 8 + o8;
        const float wv0 = swvn[o],  wv1 = swvn[16 + o],  wv2 = swvn[32 + o];
        const float wd0 = swdvn[o], wd1 = swdvn[16 + o], wd2 = swdvn[32 + o];
        float pv[3], dv[3];
        float dot = 0.f, dsq = 0.f;
#pragma unroll
        for (int d = 0; d < 3; ++d) {
            const float pp = BN_SCALE * (L[0][d] * wv0 + L[1][d] * wv1 + L[2][d] * wv2);
            const float dd = L[0][d] * wd0 + L[1][d] * wd1 + L[2][d] * wd2;
            pv[d] = pp; dv[d] = dd;
            dot += pp * dd;
            dsq += dd * dd;
        }
        const float f = dot * __builtin_amdgcn_rcpf(dsq + VN_EPS);
        float acc = 0.f;
#pragma unroll
        for (int d = 0; d < 3; ++d) {
            const float corr = pv[d] - f * dv[d];
            const float sel  = (dot >= 0.f) ? pv[d] : corr;
            const float a    = NEG * pv[d] + POS * sel;
            acc += a * a;
        }
        const float s = __builtin_amdgcn_sqrtf(acc);
        t01 += s * (*(const v2f*)&swh1[o * 8 + 0]);
        t23 += s * (*(const v2f*)&swh1[o * 8 + 2]);
        t45 += s * (*(const v2f*)&swh1[o * 8 + 4]);
        t67 += s * (*(const v2f*)&swh1[o * 8 + 6]);
    }
    // cross-half reduce: partner row holds the other 8 o's partials
    t01[0] += swz_xor16(t01[0]);  t01[1] += swz_xor16(t01[1]);
    t23[0] += swz_xor16(t23[0]);  t23[1] += swz_xor16(t23[1]);
    t45[0] += swz_xor16(t45[0]);  t45[1] += swz_xor16(t45[1]);
    t67[0] += swz_xor16(t67[0]);  t67[1] += swz_xor16(t67[1]);

    float tt[8];
    tt[0] = fmaxf(t01[0] * BN_SCALE, 0.f);  tt[1] = fmaxf(t01[1] * BN_SCALE, 0.f);
    tt[2] = fmaxf(t23[0] * BN_SCALE, 0.f);  tt[3] = fmaxf(t23[1] * BN_SCALE, 0.f);
    tt[4] = fmaxf(t45[0] * BN_SCALE, 0.f);  tt[5] = fmaxf(t45[1] * BN_SCALE, 0.f);
    tt[6] = fmaxf(t67[0] * BN_SCALE, 0.f);  tt[7] = fmaxf(t67[1] * BN_SCALE, 0.f);

    // ---- 8->8 conv + bias, softmax (w_h2/b_h2 wave-uniform -> SGPR) ------
    float sc[8];
    float mx = -1e30f;
#pragma unroll
    for (int op = 0; op < 4; ++op) {
        v2f u = *(const v2f*)&b_h2[2 * op];
#pragma unroll
        for (int c = 0; c < 8; ++c)
            u += tt[c] * (*(const v2f*)&w_h2[c * 8 + 2 * op]);
        sc[2 * op + 0] = u[0];
        sc[2 * op + 1] = u[1];
        mx = fmaxf(mx, fmaxf(u[0], u[1]));
    }
    float se = 0.f;
#pragma unroll
    for (int o = 0; o < 8; ++o) { sc[o] = __expf(sc[o] - mx); se += sc[o]; }
    const float inv_se = __builtin_amdgcn_rcpf(se);
#pragma unroll
    for (int o = 0; o < 8; ++o) sc[o] *= inv_se;

    // ---- kernel-point correlation: og half folds its 16 h's in v2f chunks
    //      (v2f keeps the W/V accumulator block at 12 regs -> no spill) ----
#pragma unroll 1
    for (int gi = 0; gi < 8; ++gi) {
        const int hb = og * 16 + gi * 2;
        v2f W0 = sc[0] * (*(const v2f*)&swb[0 * 256 + hb]);
        v2f W1 = sc[0] * (*(const v2f*)&swb[1 * 256 + hb]);
        v2f W2 = sc[0] * (*(const v2f*)&swb[2 * 256 + hb]);
#pragma unroll
        for (int s = 1; s < 8; ++s) {
            const float sv = sc[s];
            W0 += sv * (*(const v2f*)&swb[0 * 256 + s * 32 + hb]);
            W1 += sv * (*(const v2f*)&swb[1 * 256 + s * 32 + hb]);
            W2 += sv * (*(const v2f*)&swb[2 * 256 + s * 32 + hb]);
        }
        v2f V0 = L[0][0] * W0 + L[1][0] * W1 + L[2][0] * W2;
        v2f V1 = L[0][1] * W0 + L[1][1] * W1 + L[2][1] * W2;
        v2f V2 = L[0][2] * W0 + L[1][2] * W1 + L[2][2] * W2;
        const v2f vv = V0 * V0 + V1 * V1 + V2 * V2;
#pragma unroll
        for (int e = 0; e < 2; ++e) {
            const float inn = __builtin_amdgcn_rsqf(fmaxf(vv[e], 1e-24f)) * 0.0625f;
            V0[e] = row16_sum15(V0[e] * inn);
            V1[e] = row16_sum15(V1[e] * inn);
            V2[e] = row16_sum15(V2[e] * inn);
        }
        if (k == 15) {
            float* dst = out + (long)n * 192;
            *(v2f*)(dst +  0 + hb) = V0;   // feats[n][d][h], d stride 32
            *(v2f*)(dst + 32 + hb) = V1;
            *(v2f*)(dst + 64 + hb) = V2;
        }
    }
}

// k2: per point, 32 lanes (one per channel); 8 points / 256-thread block.
// Point's 32 lanes live in one wave half -> all LDS write->read traffic is
// intra-wave (in-order DS pipe), no barriers at all.
__global__ __launch_bounds__(256, 8) void areconv_post(
    const float* __restrict__ wd_relu,  // [32,32]
    const float* __restrict__ w_un,     // [32,64]
    const float* __restrict__ wd_un,    // [32,64]
    float* __restrict__ out,            // [N,64,3]; reads feats from first 96
    int N)
{
    const float BN_SCALE = 0.999994993f;

    __shared__ float sf [8][96];   // feats   [bpi][d*32+h]
    __shared__ float sf2[8][96];   // feats2

    const int tid  = threadIdx.x;
    const int wv   = tid >> 6;        // 0..3
    const int lane = tid & 63;
    const int half = lane >> 5;       // 0..1
    const int oo   = lane & 31;       // channel
    const int bpi  = wv * 2 + half;   // point slot 0..7

    // ---- stage this wave's 2 points' feats (192 floats) ------------------
    const int n0 = blockIdx.x * 8 + wv * 2;
#pragma unroll
    for (int i = lane; i < 192; i += 64) {
        const int pt = (i >= 96) ? 1 : 0;
        const int j  = i - 96 * pt;
        int nn = n0 + pt;
        nn = (nn < N) ? nn : (N - 1);
        sf[wv * 2 + pt][j] = out[(long)nn * 192 + j];
    }
    int n = blockIdx.x * 8 + bpi;
    n = (n < N) ? n : (N - 1);

    // ---- VNLeakyReLU(32->32): lane owns channel oo -----------------------
    {
        float D0 = 0.f, D1 = 0.f, D2 = 0.f;
        for (int h = 0; h < 32; ++h) {
            const float w = wd_relu[h * 32 + oo];   // coalesced, L1-resident
            D0 += sf[bpi][h]      * w;
            D1 += sf[bpi][32 + h] * w;
            D2 += sf[bpi][64 + h] * w;
        }
        const float p0 = sf[bpi][oo];
        const float p1 = sf[bpi][32 + oo];
        const float p2 = sf[bpi][64 + oo];
        const float dot = p0 * D0 + p1 * D1 + p2 * D2;
        const float dsq = D0 * D0 + D1 * D1 + D2 * D2;
        const float f   = dot * __builtin_amdgcn_rcpf(dsq + VN_EPS);
        const bool  pos = (dot >= 0.f);
        sf2[bpi][oo]      = NEG * p0 + POS * (pos ? p0 : (p0 - f * D0));
        sf2[bpi][32 + oo] = NEG * p1 + POS * (pos ? p1 : (p1 - f * D1));
        sf2[bpi][64 + oo] = NEG * p2 + POS * (pos ? p2 : (p2 - f * D2));
    }

    // ---- VNLinearLeakyReLU(32->64): lane owns o = {2oo, 2oo+1} ----------
    {
        v2f AU0 = {0.f, 0.f}, AU1 = AU0, AU2 = AU0;
        v2f AV0 = AU0, AV1 = AU0, AV2 = AU0;
        for (int h = 0; h < 32; ++h) {
            const v2f wu = *(const v2f*)&w_un [h * 64 + 2 * oo];
            const v2f wd = *(const v2f*)&wd_un[h * 64 + 2 * oo];
            const float f0 = sf2[bpi][h];
            const float f1 = sf2[bpi][32 + h];
            const float f2 = sf2[bpi][64 + h];
            AU0 += f0 * wu; AU1 += f1 * wu; AU2 += f2 * wu;
            AV0 += f0 * wd; AV1 += f1 * wd; AV2 += f2 * wd;
        }
        float O[6];
#pragma unroll
        for (int j = 0; j < 2; ++j) {
            const float u0 = AU0[j] * BN_SCALE;
            const float u1 = AU1[j] * BN_SCALE;
            const float u2 = AU2[j] * BN_SCALE;
            const float v0 = AV0[j], v1 = AV1[j], v2 = AV2[j];
            const float dot = u0 * v0 + u1 * v1 + u2 * v2;
            const float dsq = v0 * v0 + v1 * v1 + v2 * v2;
            const float f   = dot * __builtin_amdgcn_rcpf(dsq + VN_EPS);
            const bool  pos = (dot >= 0.f);
            O[3 * j + 0] = NEG * u0 + POS * (pos ? u0 : (u0 - f * v0));
            O[3 * j + 1] = NEG * u1 + POS * (pos ? u1 : (u1 - f * v1));
            O[3 * j + 2] = NEG * u2 + POS * (pos ? u2 : (u2 - f * v2));
        }
        // lane oo covers out[n, 2oo..2oo+2, :] = 6 contiguous floats; 32
        // lanes cover the point's whole 192-float slab contiguously.
        // Safe vs the staged feats: every lane's loads completed (vmcnt)
        // before its LDS writes, which precede all compute and these stores.
        float* dst = out + (long)n * 192 + 6 * oo;
        *(v2f*)(dst + 0) = *(const v2f*)&O[0];
        *(v2f*)(dst + 2) = *(const v2f*)&O[2];
        *(v2f*)(dst + 4) = *(const v2f*)&O[4];
    }
}

extern "C" void kernel_launch(void* const* d_in, const int* in_sizes, int n_in,
                              void* d_out, int out_size, void* d_ws, size_t ws_size,
                              hipStream_t stream) {
    const float* q_pts   = (const float*)d_in[0];
    const float* s_pts   = (const float*)d_in[1];
    // d_in[2] = s_feats: unused by the reference
    const int*   nbr     = (const int*)  d_in[3];
    const float* wb      = (const float*)d_in[4];
    const float* w_vn    = (const float*)d_in[5];
    const float* wd_vn   = (const float*)d_in[6];
    const float* w_h1    = (const float*)d_in[7];
    const float* w_h2    = (const float*)d_in[8];
    const float* b_h2    = (const float*)d_in[9];
    const float* wd_relu = (const float*)d_in[10];
    const float* w_un    = (const float*)d_in[11];
    const float* wd_un   = (const float*)d_in[12];
    float* out = (float*)d_out;

    const int N = in_sizes[0] / 3;          // q_pts is [N,3]
    areconv_fold<<<(N + 3) / 4, 128, 0, stream>>>(
        q_pts, s_pts, nbr, wb, w_vn, wd_vn, w_h1, w_h2, b_h2, out, N);
    areconv_post<<<(N + 7) / 8, 256, 0, stream>>>(
        wd_relu, w_un, wd_un, out, N);
}

// Round 4
// 119.166 us; speedup vs baseline: 1.3085x; 1.0483x over previous
//
#include <hip/hip_runtime.h>
#include <math.h>

#define VN_EPS   1e-6f
#define NEG      0.2f
#define POS      0.8f   // 1 - NEG

typedef float v2f __attribute__((ext_vector_type(2)));
typedef float v4f __attribute__((ext_vector_type(4)));

// ---- DPP 16-lane (row) reductions: VALU-only, HW-verified R3-R8 ------------
template <int CTRL>
__device__ __forceinline__ float dpp_add(float v) {
    int s = __builtin_amdgcn_update_dpp(0, __float_as_int(v), CTRL, 0xf, 0xf, true);
    return v + __int_as_float(s);
}
__device__ __forceinline__ float row16_allsum(float v) {
    v = dpp_add<0x128>(v);  // row_ror:8
    v = dpp_add<0x124>(v);  // row_ror:4
    v = dpp_add<0x122>(v);  // row_ror:2
    v = dpp_add<0x121>(v);  // row_ror:1
    return v;
}
__device__ __forceinline__ float row16_sum15(float v) {
    v = dpp_add<0x118>(v);  // row_shr:8
    v = dpp_add<0x114>(v);  // row_shr:4
    v = dpp_add<0x112>(v);  // row_shr:2
    v = dpp_add<0x111>(v);  // row_shr:1
    return v;
}
// lane <-> lane^16 exchange (BitMode: xor=16, and=0x1F; intra-32 only)
__device__ __forceinline__ float swz_xor16(float v) {
    return __int_as_float(__builtin_amdgcn_ds_swizzle(__float_as_int(v), 0x401F));
}
// reduce over the 4 og-quarters at fixed k: lane^16 (swizzle) + lane^32 (shfl)
__device__ __forceinline__ float og4_reduce(float v) {
    v += swz_xor16(v);
    v += __shfl_xor(v, 32, 64);
    return v;
}

// R14: 64 LANES PER POINT, single kernel, NO VGPR CAP.
// Evidence trail: R11 (cap 64) spilled 200MB; R12 (cap 80) spilled 54MB and
// ran 60us; R13's phase split left k1 at ~35-40us (cap 72 < peak-phase
// demand -> still spilling) plus a launch gap + 25MB feats round-trip.
// Conclusion: caps below natural demand convert to scratch traffic 1:1; the
// only way to cut demand is cutting per-lane STATE. Here each point gets a
// full wave: lane = og*16 + k (og in 0..3). Score-net: 4 o's per quarter,
// reduced over og via xor16+xor32 AT FIXED k (scores stay per-neighbor).
// Fold: 8 h-cols per quarter in v2f chunks. Post phases merged back (they
// run after the register peak; 1 point = 1 wave makes all LDS hand-off
// intra-wave, in-order DS pipe, zero barriers after weight staging).
// Grid: 16000 waves; natural alloc (uncapped) expected ~80-90 -> 5-6
// waves/SIMD with ZERO spill.
// NOTE (R6): scores sc[] are PER-NEIGHBOR — never dedup the fold across k.
// NOTE (R9): the fold must stay fp32 (normalize amplifies bf16 quantization).
// NOTE (R11-R13): never set a min-waves launch bound on this kernel.
__global__ __launch_bounds__(256) void areconv_all(
    const float* __restrict__ q_pts,    // [N,3]
    const float* __restrict__ s_pts,    // [N2,3]
    const int*   __restrict__ nbr,      // [N,16]
    const float* __restrict__ wb,       // [3,256]
    const float* __restrict__ w_vn,     // [3,16]
    const float* __restrict__ wd_vn,    // [3,16]
    const float* __restrict__ w_h1,     // [16,8]
    const float* __restrict__ w_h2,     // [8,8]
    const float* __restrict__ b_h2,     // [8]
    const float* __restrict__ wd_relu,  // [32,32]
    const float* __restrict__ w_un,     // [32,64]
    const float* __restrict__ wd_un,    // [32,64]
    float* __restrict__ out,            // [N,64,3]
    int N)
{
    const float BN_SCALE = 0.999994993f;  // float32(1/sqrt(1+1e-5))

    // weight tables (row-varying under og-split -> LDS broadcast reads)
    __shared__ __align__(16) float swb  [768];  // [3][256]
    __shared__ __align__(16) float swvn [48];   // [3][16]
    __shared__ __align__(16) float swdvn[48];
    __shared__ __align__(16) float swh1 [128];  // [16][8]
    // per-point hand-off buffers; wave-private (index wv), intra-wave traffic
    __shared__ __align__(16) float sfeat [4][3][32];
    __shared__ __align__(16) float sfeat2[4][3][32];

    const int tid = threadIdx.x;
    if (tid < 48)  { swvn[tid] = w_vn[tid]; swdvn[tid] = wd_vn[tid]; }
    if (tid < 128) swh1[tid] = w_h1[tid];
#pragma unroll
    for (int i = 0; i < 3; ++i) swb[tid + 256 * i] = wb[tid + 256 * i];
    __syncthreads();   // only barrier in the kernel

    const int wv   = tid >> 6;        // point slot in block (0..3)
    const int lane = tid & 63;
    const int og   = lane >> 4;       // quarter 0..3 (DPP row)
    const int k    = lane & 15;       // neighbor index
    int n = blockIdx.x * 4 + wv;
    n = (n < N) ? n : (N - 1);        // N=16000 -> never clamps

    // ---- gather + center + cross -> local frame L[c][d] ------------------
    // (all 4 quarters redundantly gather the same 16 neighbors; L1-served)
    const float qx = q_pts[n * 3 + 0];
    const float qy = q_pts[n * 3 + 1];
    const float qz = q_pts[n * 3 + 2];
    const int   id = nbr[n * 16 + k];
    const float px = s_pts[id * 3 + 0] - qx;
    const float py = s_pts[id * 3 + 1] - qy;
    const float pz = s_pts[id * 3 + 2] - qz;

    const float cx = row16_allsum(px) * 0.0625f;
    const float cy = row16_allsum(py) * 0.0625f;
    const float cz = row16_allsum(pz) * 0.0625f;

    const float rx = py * cz - pz * cy;
    const float ry = pz * cx - px * cz;
    const float rz = px * cy - py * cx;

    const float L[3][3] = {{px, py, pz}, {cx, cy, cz}, {rx, ry, rz}};

    // ---- score net: quarter does 4 of the 16 o's, reduce over og ---------
    v2f t01 = {0.f, 0.f}, t23 = t01, t45 = t01, t67 = t01;
#pragma unroll 1
    for (int o4 = 0; o4 < 4; ++o4) {
        const int o = og * 4 + o4;
        const float wv0 = swvn[o],  wv1 = swvn[16 + o],  wv2 = swvn[32 + o];
        const float wd0 = swdvn[o], wd1 = swdvn[16 + o], wd2 = swdvn[32 + o];
        float pv[3], dv[3];
        float dot = 0.f, dsq = 0.f;
#pragma unroll
        for (int d = 0; d < 3; ++d) {
            const float pp = BN_SCALE * (L[0][d] * wv0 + L[1][d] * wv1 + L[2][d] * wv2);
            const float dd = L[0][d] * wd0 + L[1][d] * wd1 + L[2][d] * wd2;
            pv[d] = pp; dv[d] = dd;
            dot += pp * dd;
            dsq += dd * dd;
        }
        const float f = dot * __builtin_amdgcn_rcpf(dsq + VN_EPS);
        float acc = 0.f;
#pragma unroll
        for (int d = 0; d < 3; ++d) {
            const float corr = pv[d] - f * dv[d];
            const float sel  = (dot >= 0.f) ? pv[d] : corr;
            const float a    = NEG * pv[d] + POS * sel;
            acc += a * a;
        }
        const float s = __builtin_amdgcn_sqrtf(acc);
        t01 += s * (*(const v2f*)&swh1[o * 8 + 0]);
        t23 += s * (*(const v2f*)&swh1[o * 8 + 2]);
        t45 += s * (*(const v2f*)&swh1[o * 8 + 4]);
        t67 += s * (*(const v2f*)&swh1[o * 8 + 6]);
    }
    // sum the 4 quarters' partials at fixed k (partner lanes share k)
    t01[0] = og4_reduce(t01[0]);  t01[1] = og4_reduce(t01[1]);
    t23[0] = og4_reduce(t23[0]);  t23[1] = og4_reduce(t23[1]);
    t45[0] = og4_reduce(t45[0]);  t45[1] = og4_reduce(t45[1]);
    t67[0] = og4_reduce(t67[0]);  t67[1] = og4_reduce(t67[1]);

    float tt[8];
    tt[0] = fmaxf(t01[0] * BN_SCALE, 0.f);  tt[1] = fmaxf(t01[1] * BN_SCALE, 0.f);
    tt[2] = fmaxf(t23[0] * BN_SCALE, 0.f);  tt[3] = fmaxf(t23[1] * BN_SCALE, 0.f);
    tt[4] = fmaxf(t45[0] * BN_SCALE, 0.f);  tt[5] = fmaxf(t45[1] * BN_SCALE, 0.f);
    tt[6] = fmaxf(t67[0] * BN_SCALE, 0.f);  tt[7] = fmaxf(t67[1] * BN_SCALE, 0.f);

    // ---- 8->8 conv + bias, softmax (per-k; w_h2/b_h2 uniform -> SGPR) ----
    float sc[8];
    float mx = -1e30f;
#pragma unroll
    for (int op = 0; op < 4; ++op) {
        v2f u = *(const v2f*)&b_h2[2 * op];
#pragma unroll
        for (int c = 0; c < 8; ++c)
            u += tt[c] * (*(const v2f*)&w_h2[c * 8 + 2 * op]);
        sc[2 * op + 0] = u[0];
        sc[2 * op + 1] = u[1];
        mx = fmaxf(mx, fmaxf(u[0], u[1]));
    }
    float se = 0.f;
#pragma unroll
    for (int o = 0; o < 8; ++o) { sc[o] = __expf(sc[o] - mx); se += sc[o]; }
    const float inv_se = __builtin_amdgcn_rcpf(se);
#pragma unroll
    for (int o = 0; o < 8; ++o) sc[o] *= inv_se;

    // ---- kernel-point correlation: quarter folds its 8 h's, v2f chunks ---
#pragma unroll 1
    for (int gi = 0; gi < 4; ++gi) {
        const int hb = og * 8 + gi * 2;
        v2f W0 = sc[0] * (*(const v2f*)&swb[0 * 256 + hb]);
        v2f W1 = sc[0] * (*(const v2f*)&swb[1 * 256 + hb]);
        v2f W2 = sc[0] * (*(const v2f*)&swb[2 * 256 + hb]);
#pragma unroll
        for (int s = 1; s < 8; ++s) {   // full unroll: sc[] stays in regs
            const float sv = sc[s];
            W0 += sv * (*(const v2f*)&swb[0 * 256 + s * 32 + hb]);
            W1 += sv * (*(const v2f*)&swb[1 * 256 + s * 32 + hb]);
            W2 += sv * (*(const v2f*)&swb[2 * 256 + s * 32 + hb]);
        }
        v2f V0 = L[0][0] * W0 + L[1][0] * W1 + L[2][0] * W2;
        v2f V1 = L[0][1] * W0 + L[1][1] * W1 + L[2][1] * W2;
        v2f V2 = L[0][2] * W0 + L[1][2] * W1 + L[2][2] * W2;
        const v2f vv = V0 * V0 + V1 * V1 + V2 * V2;
#pragma unroll
        for (int e = 0; e < 2; ++e) {
            const float inn = __builtin_amdgcn_rsqf(fmaxf(vv[e], 1e-24f)) * 0.0625f;
            V0[e] = row16_sum15(V0[e] * inn);
            V1[e] = row16_sum15(V1[e] * inn);
            V2[e] = row16_sum15(V2[e] * inn);
        }
        if (k == 15) {   // 4 writer lanes per wave, disjoint h ranges
            *(v2f*)&sfeat[wv][0][hb] = V0;
            *(v2f*)&sfeat[wv][1][hb] = V1;
            *(v2f*)&sfeat[wv][2][hb] = V2;
        }
    }
    // intra-wave LDS write->read from here on (in-order DS pipe, no barrier)

    // ---- VNLeakyReLU(32->32): lane owns channel oo (halves redundant) ----
    const int oo = lane & 31;
    {
        float D0 = 0.f, D1 = 0.f, D2 = 0.f;
#pragma unroll 1
        for (int hq = 0; hq < 8; ++hq) {
            const v4f f0 = *(const v4f*)&sfeat[wv][0][hq * 4];
            const v4f f1 = *(const v4f*)&sfeat[wv][1][hq * 4];
            const v4f f2 = *(const v4f*)&sfeat[wv][2][hq * 4];
#pragma unroll
            for (int e = 0; e < 4; ++e) {
                const float w = wd_relu[(hq * 4 + e) * 32 + oo];
                D0 += f0[e] * w;
                D1 += f1[e] * w;
                D2 += f2[e] * w;
            }
        }
        const float p0 = sfeat[wv][0][oo];
        const float p1 = sfeat[wv][1][oo];
        const float p2 = sfeat[wv][2][oo];
        const float dot = p0 * D0 + p1 * D1 + p2 * D2;
        const float dsq = D0 * D0 + D1 * D1 + D2 * D2;
        const float f   = dot * __builtin_amdgcn_rcpf(dsq + VN_EPS);
        const bool  pos = (dot >= 0.f);
        if (lane < 32) {   // one writer per channel
            sfeat2[wv][0][oo] = NEG * p0 + POS * (pos ? p0 : (p0 - f * D0));
            sfeat2[wv][1][oo] = NEG * p1 + POS * (pos ? p1 : (p1 - f * D1));
            sfeat2[wv][2][oo] = NEG * p2 + POS * (pos ? p2 : (p2 - f * D2));
        }
    }

    // ---- VNLinearLeakyReLU(32->64): lane owns output channel o = lane ----
    {
        float AU0 = 0.f, AU1 = 0.f, AU2 = 0.f;
        float AV0 = 0.f, AV1 = 0.f, AV2 = 0.f;
#pragma unroll 1
        for (int hq = 0; hq < 8; ++hq) {
            const v4f f0 = *(const v4f*)&sfeat2[wv][0][hq * 4];
            const v4f f1 = *(const v4f*)&sfeat2[wv][1][hq * 4];
            const v4f f2 = *(const v4f*)&sfeat2[wv][2][hq * 4];
#pragma unroll
            for (int e = 0; e < 4; ++e) {
                const float wu = w_un [(hq * 4 + e) * 64 + lane];
                const float wd = wd_un[(hq * 4 + e) * 64 + lane];
                AU0 += f0[e] * wu; AU1 += f1[e] * wu; AU2 += f2[e] * wu;
                AV0 += f0[e] * wd; AV1 += f1[e] * wd; AV2 += f2[e] * wd;
            }
        }
        const float u0 = AU0 * BN_SCALE;
        const float u1 = AU1 * BN_SCALE;
        const float u2 = AU2 * BN_SCALE;
        const float dot = u0 * AV0 + u1 * AV1 + u2 * AV2;
        const float dsq = AV0 * AV0 + AV1 * AV1 + AV2 * AV2;
        const float f   = dot * __builtin_amdgcn_rcpf(dsq + VN_EPS);
        const bool  pos = (dot >= 0.f);
        const float O0 = NEG * u0 + POS * (pos ? u0 : (u0 - f * AV0));
        const float O1 = NEG * u1 + POS * (pos ? u1 : (u1 - f * AV1));
        const float O2 = NEG * u2 + POS * (pos ? u2 : (u2 - f * AV2));
        // lane o writes out[n, o, 0..2]; 64 lanes cover the 192-float slab.
        // (12 B stride -> only 4-aligned at odd o: scalar stores)
        float* dst = out + (long)n * 192 + 3 * lane;
        dst[0] = O0;
        dst[1] = O1;
        dst[2] = O2;
    }
}

extern "C" void kernel_launch(void* const* d_in, const int* in_sizes, int n_in,
                              void* d_out, int out_size, void* d_ws, size_t ws_size,
                              hipStream_t stream) {
    const float* q_pts   = (const float*)d_in[0];
    const float* s_pts   = (const float*)d_in[1];
    // d_in[2] = s_feats: unused by the reference
    const int*   nbr     = (const int*)  d_in[3];
    const float* wb      = (const float*)d_in[4];
    const float* w_vn    = (const float*)d_in[5];
    const float* wd_vn   = (const float*)d_in[6];
    const float* w_h1    = (const float*)d_in[7];
    const float* w_h2    = (const float*)d_in[8];
    const float* b_h2    = (const float*)d_in[9];
    const float* wd_relu = (const float*)d_in[10];
    const float* w_un    = (const float*)d_in[11];
    const float* wd_un   = (const float*)d_in[12];
    float* out = (float*)d_out;

    const int N = in_sizes[0] / 3;          // q_pts is [N,3]
    const int blocks = (N + 3) / 4;         // 4 points/block, 1 per wave
    areconv_all<<<blocks, 256, 0, stream>>>(
        q_pts, s_pts, nbr, wb, w_vn, wd_vn, w_h1, w_h2, b_h2,
        wd_relu, w_un, wd_un, out, N);
}